// Round 5
// baseline (5732.521 us; speedup 1.0000x reference)
//
#include <hip/hip_runtime.h>
#include <stdint.h>

// ---------------------------------------------------------------------------
// 2-layer LSTM, B=64, T=512, E=512, H=1024, then [64,1024]@V.T+bV -> [64,10].
//
// Round 9: R8 geometry, PROVEN primitives. 8 clusters of 32 WGs (1/XCD,
// runtime-verified via HW_REG_XCC_ID vote; else exact-R7 fallback):
//   xcd 0,1: L0a(g)  Wh0*h0(t-1)  spine: local ring, plain reads + buffer_inv
//   xcd 2,3: L1a(g)  Wh1*h1(t-1)  spine: local ring + hpart add, h1f
//   xcd 4,5: L0b(g)  Wx*x(t)      runs ahead, ships f32 xpart (agent atomics)
//   xcd 6,7: L1b(g)  Wih*h0(t)    reads h0g via ldh (agent), ships hpart
// R8's absmax~3e-2 was stable across sync fixes -> cache-semantics bug in the
// invented sc0/sc01 primitives. All flags+cross-XCD data now use R7-proven
// __hip_atomic AGENT ops; local ring = agent stores + plain dwordx4 reads +
// one buffer_inv (L1 inv) per tick (sound under any L1/L2 model).
// Backpressure (R8c) kept: FL_GD publishes L1a progress; L0a wave1 gates h0g.
// ---------------------------------------------------------------------------

typedef __attribute__((ext_vector_type(8))) short bf16x8;
typedef __attribute__((ext_vector_type(4))) float f32x4;
typedef unsigned short ush;
typedef unsigned int u32;

__device__ __forceinline__ ush f2bf(float x) {
    unsigned u = __float_as_uint(x);
    u = (u + 0x7FFFu + ((u >> 16) & 1u)) >> 16;   // RNE
    return (ush)u;
}

__device__ __forceinline__ f32x4 mfma16(bf16x8 a, bf16x8 b, f32x4 c) {
    return __builtin_amdgcn_mfma_f32_16x16x32_bf16(a, b, c, 0, 0, 0);
}

__device__ __forceinline__ float fsigm(float x) {
    x = fminf(fmaxf(x, -60.f), 60.f);
    return __builtin_amdgcn_rcpf(1.f + __expf(-x));
}
__device__ __forceinline__ float ftanh(float x) {
    x = fminf(fmaxf(x, -15.f), 15.f);
    float e = __expf(-2.f * x);
    return (1.f - e) * __builtin_amdgcn_rcpf(1.f + e);
}

// ---- proven access primitives --------------------------------------------
__device__ __forceinline__ u32 aload(const u32* p) {
    return __hip_atomic_load(p, __ATOMIC_RELAXED, __HIP_MEMORY_SCOPE_AGENT);
}
__device__ __forceinline__ void astore(u32* p, u32 v) {
    __hip_atomic_store(p, v, __ATOMIC_RELAXED, __HIP_MEMORY_SCOPE_AGENT);
}
__device__ __forceinline__ float aloadf(const float* p) {
    return __hip_atomic_load(p, __ATOMIC_RELAXED, __HIP_MEMORY_SCOPE_AGENT);
}
__device__ __forceinline__ void astoref(float* p, float v) {
    __hip_atomic_store(p, v, __ATOMIC_RELAXED, __HIP_MEMORY_SCOPE_AGENT);
}
// agent-scope 16B load (IC-direct, R3/R7-proven)
__device__ __forceinline__ bf16x8 ldh(const ush* p) {
    union { unsigned long long q[2]; bf16x8 v; } u;
    unsigned long long* a = (unsigned long long*)p;
    u.q[0] = __hip_atomic_load(a + 0, __ATOMIC_RELAXED, __HIP_MEMORY_SCOPE_AGENT);
    u.q[1] = __hip_atomic_load(a + 1, __ATOMIC_RELAXED, __HIP_MEMORY_SCOPE_AGENT);
    return u.v;
}
#define WAITVM0() do { asm volatile("s_waitcnt vmcnt(0)" ::: "memory"); \
                       __builtin_amdgcn_sched_barrier(0); } while (0)
#define L1INV()  do { asm volatile("buffer_inv" ::: "memory"); \
                      __builtin_amdgcn_sched_barrier(0); } while (0)
__device__ __forceinline__ void barlg() {
    asm volatile("s_waitcnt lgkmcnt(0)\ns_barrier" ::: "memory");
    __builtin_amdgcn_sched_barrier(0);
}

__device__ __forceinline__ void poll64(const u32* base, int lane, unsigned target) {
    const u32* p = base + lane;
    for (;;) {
        unsigned a = aload(p);
        if (__all((int)(a >= target))) break;
        __builtin_amdgcn_s_sleep(2);
    }
}
__device__ __forceinline__ void poll128(const u32* base, int lane, unsigned target) {
    const u32* p0 = base + lane;
    const u32* p1 = base + 64 + lane;
    for (;;) {
        unsigned a = aload(p0);
        unsigned b = aload(p1);
        if (__all((int)((a >= target) && (b >= target)))) break;
        __builtin_amdgcn_s_sleep(2);
    }
}

// ---------------- embedding gather + bf16 convert --------------------------
__global__ __launch_bounds__(256) void embed_kernel(
    const int* __restrict__ x, const float* __restrict__ emb,
    ush* __restrict__ xs)
{
    int e = blockIdx.x * 256 + threadIdx.x;
    int t  = e >> 12;
    int rr = e & 4095;
    int b  = rr >> 6;
    int k8 = (rr & 63) << 3;
    int tok = x[b * 512 + t];
    const float* src = emb + (size_t)tok * 512 + k8;
    ush* dst = xs + ((size_t)(t * 64 + b)) * 512 + k8;
#pragma unroll
    for (int i = 0; i < 8; ++i) dst[i] = f2bf(src[i]);
}

__global__ __launch_bounds__(256) void init_kernel(u32* __restrict__ p, int n)
{
    int i = blockIdx.x * 256 + threadIdx.x;
    if (i < n) p[i] = 0u;
}

// ---- layout ---------------------------------------------------------------
#define SLOTH 32768          // ushorts per h slot (32 rows x 1024)
#define SLOTP 131072         // floats per partial slot (32 rows x 4096)
#define OFF_H0G 33554432ULL  // [2][32][SLOTH] bf16  (4 MB)
#define OFF_H0L 37748736ULL  // [2][16][SLOTH]       (2 MB)
#define OFF_H1L 39845888ULL  // [2][16][SLOTH]       (2 MB)
#define OFF_XP  41943040ULL  // [2][8][SLOTP] f32    (8 MB)
#define OFF_HP  50331648ULL  // [2][8][SLOTP] f32    (8 MB)
#define OFF_FL  58720256ULL  // flags
#define OFF_H1F 67108864ULL
#define OFF_BAR 67371008ULL  // fallback flag banks (R7)
#define FL_LOC  0            // [8][32] cluster-local flags
#define FL_GA   256          // [2][32] L0a global progress
#define FL_GB   320          // [2][32] L0b xpart progress
#define FL_GLB  384          // [2][32] L1b hpart progress
#define FL_GD   448          // [2][32] L1a progress (hpart backpressure)
#define FL_DISC 512
// fallback (R7/R3) defines
#define LDS_GWS_OFF 131072
#define GWS_TILE    272
#define RELIDX      2048
#define RING_MASK   127
#define SLOT_USH    65536
#define NBANK       16
#define LDS_LOCAL_TOTAL 151616   // 131072 Afrag + 16 tiles * 321 * 4
#define LDS_FB_TOTAL    148480

// ====================== FALLBACK: exact R7 dataflow path ====================
__device__ void fallback_df(char* smem, const ush* xs,
    ush* h0ring, ush* h1ring, float* h1f, u32* bar,
    const float* W0, const float* b0, const float* W1, const float* b1,
    int wg, int tid)
{
    bf16x8* Afrag = (bf16x8*)smem;
    float*  gws   = (float*)(smem + LDS_GWS_OFF);

    const bool isL1 = (wg >= 128);
    const int rr  = wg & 127;
    const int g   = rr >> 6;
    const int w   = rr & 63;
    const int w16 = w * 16;
    const float* W = isL1 ? W1 : W0;
    const int wstride = isL1 ? 2048 : 1536;
    const float* bias = isL1 ? b1 : b0;
    const u32* bk = bar + (wg & (NBANK - 1)) * 256;

    for (int f = tid; f < 8192; f += 512) {
        int laneE = f & 63;
        int gt    = (f >> 6) & 3;
        int kb    = f >> 8;
        int m16   = laneE & 15;
        int q     = laneE >> 4;
        int c     = m16 >> 2;
        int s     = m16 & 3;
        int grow  = c * 1024 + w16 + gt * 4 + s;
        const float* src = W + (size_t)grow * wstride + kb * 32 + q * 8;
        bf16x8 v;
#pragma unroll
        for (int i = 0; i < 8; ++i) v[i] = (short)f2bf(src[i]);
        Afrag[f] = v;
    }

    const int lane = tid & 63;
    const int wid  = tid >> 6;
    const int bt   = wid & 1;
    const int ksh  = wid >> 1;
    const int n16  = lane & 15;
    const int q4   = lane >> 4;
    const int row  = g * 32 + bt * 16 + n16;
    const int nkreg = isL1 ? 8 : 4;

    bf16x8 rfb[8][4];
    {
        int m16 = lane & 15;
        int q   = lane >> 4;
        int c   = m16 >> 2;
        int s   = m16 & 3;
#pragma unroll
        for (int jr = 0; jr < 8; ++jr) {
            if (jr < nkreg) {
                int kb = 32 + ksh + 4 * jr;
#pragma unroll
                for (int gt = 0; gt < 4; ++gt) {
                    int grow = c * 1024 + w16 + gt * 4 + s;
                    const float* src = W + (size_t)grow * wstride + kb * 32 + q * 8;
                    bf16x8 v;
#pragma unroll
                    for (int i = 0; i < 8; ++i) v[i] = (short)f2bf(src[i]);
                    rfb[jr][gt] = v;
                }
            }
        }
    }

    const int eb   = tid >> 4;
    const int ecol = tid & 15;
    const int ebt  = tid >> 8;
    const int en   = eb & 15;
    const int egt  = ecol >> 2;
    const int es   = ecol & 3;
    const int erow = g * 32 + eb;
    float bi[4];
#pragma unroll
    for (int c = 0; c < 4; ++c) bi[c] = bias[c * 1024 + w16 + ecol];
    float cst = 0.f;
    const float* gs0 = gws + (size_t)((ebt * 2 + 0) * 4 + egt) * GWS_TILE + es * 17 + en;
    const float* gs1 = gws + (size_t)((ebt * 2 + 1) * 4 + egt) * GWS_TILE + es * 17 + en;
    float* gwr = gws + (size_t)((bt * 2 + (ksh & 1)) * 4) * GWS_TILE + q4 * 68 + n16;

    __syncthreads();

    f32x4 acc[4];
#pragma unroll
    for (int i = 0; i < 4; ++i) acc[i] = (f32x4){0.f, 0.f, 0.f, 0.f};

    if (!isL1) {
        const ush* xsp = xs + ((size_t)row) * 512 + q4 * 8;
#pragma unroll
        for (int j = 0; j < 4; ++j) {
            int kb = ksh + 4 * j;
            bf16x8 bf = *(const bf16x8*)(xsp + kb * 32);
#pragma unroll
            for (int gt = 0; gt < 4; ++gt)
                acc[gt] = mfma16(Afrag[(kb * 4 + gt) * 64 + lane], bf, acc[gt]);
        }
    }

    for (int tick = 0; tick < 513; ++tick) {
        if (tick > 0) {
            unsigned target = (unsigned)tick;
            if ((tick & RING_MASK) == 0) {
                if (wid == 0)      poll128(bk,       lane, target);
                else if (wid == 4) poll128(bk + 128, lane, target);
                __syncthreads();
                if (wid == 0)
                    __builtin_amdgcn_fence(__ATOMIC_ACQUIRE, "agent");
                __syncthreads();
            } else {
                if (wid == 0)              poll64(bk + g * 64, lane, target);
                else if (isL1 && wid == 4) poll64(bk + 128 + g * 64, lane, target);
                __syncthreads();
            }
        }

        int t = isL1 ? (tick - 1) : tick;
        if (t >= 0 && t < 512) {
            if (!isL1) {
                if (t > 0) {
                    const ush* hp =
                        h0ring + (size_t)((t - 1) & RING_MASK) * SLOT_USH
                               + (size_t)row * 1024 + q4 * 8;
#pragma unroll
                    for (int j = 4; j < 8; ++j) {
                        int kb = ksh + 4 * j;
                        bf16x8 bf = *(const bf16x8*)(hp + (kb - 16) * 32);
#pragma unroll
                        for (int gt = 0; gt < 4; ++gt)
                            acc[gt] = mfma16(Afrag[(kb * 4 + gt) * 64 + lane], bf, acc[gt]);
                    }
#pragma unroll
                    for (int j = 0; j < 4; ++j) {
                        int kb = 32 + ksh + 4 * j;
                        bf16x8 bf = *(const bf16x8*)(hp + (kb - 16) * 32);
#pragma unroll
                        for (int gt = 0; gt < 4; ++gt)
                            acc[gt] = mfma16(rfb[j][gt], bf, acc[gt]);
                    }
                }
            } else {
                const ush* hp0 =
                    h0ring + (size_t)(t & RING_MASK) * SLOT_USH
                           + (size_t)row * 1024 + q4 * 8;
#pragma unroll
                for (int j = 0; j < 8; ++j) {
                    int kb = ksh + 4 * j;
                    bf16x8 bf = *(const bf16x8*)(hp0 + kb * 32);
#pragma unroll
                    for (int gt = 0; gt < 4; ++gt)
                        acc[gt] = mfma16(Afrag[(kb * 4 + gt) * 64 + lane], bf, acc[gt]);
                }
                if (t > 0) {
                    const ush* hp1 =
                        h1ring + (size_t)((t - 1) & RING_MASK) * SLOT_USH
                               + (size_t)row * 1024 + q4 * 8;
#pragma unroll
                    for (int j = 0; j < 8; ++j) {
                        int kb = ksh + 4 * j;
                        bf16x8 bf = *(const bf16x8*)(hp1 + kb * 32);
#pragma unroll
                        for (int gt = 0; gt < 4; ++gt)
                            acc[gt] = mfma16(rfb[j][gt], bf, acc[gt]);
                    }
                }
            }

            if (ksh < 2) {
#pragma unroll
                for (int gt = 0; gt < 4; ++gt)
#pragma unroll
                    for (int r2 = 0; r2 < 4; ++r2)
                        gwr[gt * GWS_TILE + r2 * 17] = acc[gt][r2];
            }
            __syncthreads();
            if (ksh >= 2) {
#pragma unroll
                for (int gt = 0; gt < 4; ++gt)
#pragma unroll
                    for (int r2 = 0; r2 < 4; ++r2)
                        gwr[gt * GWS_TILE + r2 * 17] += acc[gt][r2];
            }
            __syncthreads();

            float xi = gs0[0]   + gs1[0]   + bi[0];
            float xf = gs0[68]  + gs1[68]  + bi[1];
            float xg = gs0[136] + gs1[136] + bi[2];
            float xo = gs0[204] + gs1[204] + bi[3];
            float si = fsigm(xi);
            float sf = fsigm(xf);
            float tg = ftanh(xg);
            float so = fsigm(xo);
            float cn = sf * cst + si * tg;
            cst = cn;
            float h  = so * ftanh(cn);
            unsigned hb  = (unsigned)f2bf(h);
            unsigned hup = (unsigned)__shfl_down((int)hb, 1);
            if (!(tid & 1)) {
                unsigned hv = hb | (hup << 16);
                ush* hw = (isL1 ? h1ring : h0ring) + (size_t)(t & RING_MASK) * SLOT_USH;
                u32* hp32 = (u32*)(hw + (size_t)erow * 1024 + w16 + ecol);
                astore(hp32, hv);
            }
            if (isL1 && t == 511)
                h1f[(size_t)erow * 1024 + w16 + ecol] = h;
            __syncthreads();
        }

        if (tick < 512) {
            if (tid < NBANK) {
                astore(bar + tid * 256 + (isL1 ? 128 : 0) + g * 64 + w,
                       (unsigned)(tick + 1));
            }
#pragma unroll
            for (int i = 0; i < 4; ++i) acc[i] = (f32x4){0.f, 0.f, 0.f, 0.f};
            int tn = tick + 1;
            if (!isL1 && tn < 512) {
                const ush* xsp = xs + ((size_t)(tn * 64 + row)) * 512 + q4 * 8;
#pragma unroll
                for (int j = 0; j < 4; ++j) {
                    int kb = ksh + 4 * j;
                    bf16x8 bf = *(const bf16x8*)(xsp + kb * 32);
#pragma unroll
                    for (int gt = 0; gt < 4; ++gt)
                        acc[gt] = mfma16(Afrag[(kb * 4 + gt) * 64 + lane], bf, acc[gt]);
                }
            }
        }
    }
}

// ====================== LOCAL: XCD-clustered path ===========================
__device__ void run_local(char* smem, char* ws, const ush* xs,
    const float* W0, const float* b0, const float* W1, const float* b1,
    int wg, int tid)
{
    const int c   = wg & 7;        // cluster == XCD (verified)
    const int r   = wg >> 3;       // rank in cluster, 0..31
    const int rid = c >> 1;        // 0=L0a 1=L1a 2=L0b 3=L1b
    const int g   = c & 1;
    const int w32 = r * 32;

    const float* W   = (rid == 0 || rid == 2) ? W0 : W1;
    const int  wst   = (rid == 0 || rid == 2) ? 1536 : 2048;
    const int  kofs  = (rid == 0) ? 512 : (rid == 1) ? 1024 : 0;

    bf16x8* Afrag = (bf16x8*)smem;
    float*  gws   = (float*)(smem + 131072);   // 16 tiles * 321 floats

    ush* h0g = (ush*)(ws + OFF_H0G) + (size_t)g * 32 * SLOTH;
    ush* h0l = (ush*)(ws + OFF_H0L) + (size_t)g * 16 * SLOTH;
    ush* h1l = (ush*)(ws + OFF_H1L) + (size_t)g * 16 * SLOTH;
    float* xpart = (float*)(ws + OFF_XP) + (size_t)g * 8 * SLOTP;
    float* hpart = (float*)(ws + OFF_HP) + (size_t)g * 8 * SLOTP;
    float* h1f   = (float*)(ws + OFF_H1F);
    u32*   FL    = (u32*)(ws + OFF_FL);

    // ---- stage LDS A: kb 0..15, 8 gate-tiles, 64 lanes (128 KB) ----
    for (int f = tid; f < 8192; f += 512) {
        int laneE = f & 63;
        int gt    = (f >> 6) & 7;
        int kb    = f >> 9;
        int m16   = laneE & 15;
        int q     = laneE >> 4;
        int cA    = m16 >> 2;
        int sA    = m16 & 3;
        int grow  = cA * 1024 + w32 + gt * 4 + sA;
        const float* src = W + (size_t)grow * wst + kofs + kb * 32 + q * 8;
        bf16x8 v;
#pragma unroll
        for (int i = 0; i < 8; ++i) v[i] = (short)f2bf(src[i]);
        Afrag[f] = v;
    }

    const int lane = tid & 63;
    const int wid  = tid >> 6;
    const int bt   = wid & 1;      // batch sub-tile (16 rows)
    const int kq   = wid >> 1;     // K-quarter 0..3
    const int n16  = lane & 15;
    const int q4   = lane >> 4;
    const int rowL = bt * 16 + n16;

    // ---- stage register A: kb = 16 + kq + 4*jr (rid 0,1,3) ----
    bf16x8 rf[4][8];
    if (rid != 2) {
        int m16 = lane & 15, q = lane >> 4;
        int cA = m16 >> 2, sA = m16 & 3;
#pragma unroll
        for (int jr = 0; jr < 4; ++jr) {
            int kb = 16 + kq + 4 * jr;
#pragma unroll
            for (int gt = 0; gt < 8; ++gt) {
                int grow = cA * 1024 + w32 + gt * 4 + sA;
                const float* src = W + (size_t)grow * wst + kofs + kb * 32 + q * 8;
                bf16x8 v;
#pragma unroll
                for (int i = 0; i < 8; ++i) v[i] = (short)f2bf(src[i]);
                rf[jr][gt] = v;
            }
        }
    }

    // ---- epilogue/ship thread mapping ----
    const int ecc = tid & 15;      // base col (cc = ecc + 16*h)
    const int b   = tid >> 4;      // group-local batch row 0..31
    const int btE = b >> 4;
    const int nE  = b & 15;
    const bool evenT = !(tid & 1);

    __syncthreads();

    if (rid <= 1) {
        // =============== RECURRENT spine (L0a / L1a) ===============
        ush* ringL = (rid == 0) ? h0l : h1l;
        const float* part = (rid == 0) ? xpart : hpart;
        u32* locfl  = FL + FL_LOC + c * 32;
        u32* partfl = FL + ((rid == 0) ? FL_GB : FL_GLB) + g * 32 + r;
        const float* bs = (rid == 0) ? b0 : b1;
        float bi[2][4];
#pragma unroll
        for (int h = 0; h < 2; ++h)
#pragma unroll
            for (int cg = 0; cg < 4; ++cg)
                bi[h][cg] = bs[cg * 1024 + w32 + ecc + 16 * h];
        float cst[2] = {0.f, 0.f};

        for (int t = 0; t < 512; ++t) {
            // ---- dependency wait (agent-atomic polls, proven) ----
            if (wid == 0) {
                const u32* pp; unsigned tgt;
                if (lane < 32) { pp = locfl + lane; tgt = (unsigned)t; }
                else           { pp = partfl; tgt = (lane == 32) ? (unsigned)(t + 1) : 0u; }
                for (;;) {
                    unsigned v = aload(pp);
                    if (__all((int)(v >= tgt))) break;
                    __builtin_amdgcn_s_sleep(2);
                }
            } else if (rid == 0 && wid == 1) {
                // h0g backpressure: all 32 L1b WGs started tick >= t-25
                const u32* pp = FL + FL_GLB + g * 32 + (lane & 31);
                unsigned tgt = (t >= 26 && lane < 32) ? (unsigned)(t - 25) : 0u;
                for (;;) {
                    unsigned v = aload(pp);
                    if (__all((int)(v >= tgt))) break;
                    __builtin_amdgcn_s_sleep(2);
                }
            }
            barlg();

            // ---- local ring B (plain 16B reads after L1 invalidate) ----
            bf16x8 B[8];
            f32x4 acc[8];
#pragma unroll
            for (int i = 0; i < 8; ++i) acc[i] = (f32x4){0.f, 0.f, 0.f, 0.f};
            if (t > 0) {
                L1INV();
                const ush* bp = ringL + (size_t)((t - 1) & 15) * SLOTH
                              + (size_t)rowL * 1024 + q4 * 8;
#pragma unroll
                for (int j = 0; j < 8; ++j) B[j] = *(const bf16x8*)(bp + (kq + 4 * j) * 32);
            }
            float xp[8];
            {
                const float* pp = part + (size_t)(t & 7) * SLOTP + (size_t)b * 4096 + w32;
#pragma unroll
                for (int h = 0; h < 2; ++h)
#pragma unroll
                    for (int cg = 0; cg < 4; ++cg)
                        xp[h * 4 + cg] = aloadf(pp + cg * 1024 + ecc + 16 * h);
            }
            if (t > 0) {
#pragma unroll
                for (int j = 0; j < 8; ++j) {
                    int kb = kq + 4 * j;
#pragma unroll
                    for (int gt = 0; gt < 8; ++gt) {
                        bf16x8 a = (j < 4) ? Afrag[(kb * 8 + gt) * 64 + lane] : rf[j - 4][gt];
                        acc[gt] = mfma16(a, B[j], acc[gt]);
                    }
                }
            }

            // ---- reduce + epilogue, two gate-column halves ----
            u32 hvA = 0, hvB = 0;
#pragma unroll
            for (int h = 0; h < 2; ++h) {
                if (kq < 2) {
#pragma unroll
                    for (int gt2 = 0; gt2 < 4; ++gt2)
#pragma unroll
                        for (int r2 = 0; r2 < 4; ++r2)
                            gws[(size_t)((bt * 2 + kq) * 4 + gt2) * 321
                                + (q4 * 4 + r2) * 20 + n16] = acc[h * 4 + gt2][r2];
                }
                barlg();
                if (kq >= 2) {
#pragma unroll
                    for (int gt2 = 0; gt2 < 4; ++gt2)
#pragma unroll
                        for (int r2 = 0; r2 < 4; ++r2)
                            gws[(size_t)((bt * 2 + (kq - 2)) * 4 + gt2) * 321
                                + (q4 * 4 + r2) * 20 + n16] += acc[h * 4 + gt2][r2];
                }
                barlg();

                int cc  = ecc + 16 * h;
                int gt2 = (cc >> 2) & 3;
                int s2  = cc & 3;
                const float* g0 = gws + (size_t)((btE * 2 + 0) * 4 + gt2) * 321 + s2 * 20 + nE;
                const float* g1 = gws + (size_t)((btE * 2 + 1) * 4 + gt2) * 321 + s2 * 20 + nE;
                float xi = g0[0]   + g1[0]   + xp[h * 4 + 0] + bi[h][0];
                float xf = g0[80]  + g1[80]  + xp[h * 4 + 1] + bi[h][1];
                float xg = g0[160] + g1[160] + xp[h * 4 + 2] + bi[h][2];
                float xo = g0[240] + g1[240] + xp[h * 4 + 3] + bi[h][3];
                float si = fsigm(xi);
                float sf = fsigm(xf);
                float tg = ftanh(xg);
                float so = fsigm(xo);
                float cn = sf * cst[h] + si * tg;
                cst[h] = cn;
                float hval = so * ftanh(cn);
                if (rid == 1 && t == 511)
                    h1f[(size_t)(g * 32 + b) * 1024 + w32 + cc] = hval;
                unsigned hb = (unsigned)f2bf(hval);
                unsigned up = (unsigned)__shfl_down((int)hb, 1);
                unsigned hv = hb | (up << 16);
                if (h == 0) hvA = hv; else hvB = hv;
                if (evenT) {
                    u32* rs = (u32*)(ringL + (size_t)(t & 15) * SLOTH);
                    astore(rs + ((b * 1024 + w32 + cc) >> 1), hv);
                }
                barlg();   // gws reuse guard
            }

            WAITVM0();     // drain ring stores before flags
            barlg();
            if (tid == 0)
                astore(locfl + r, (u32)(t + 1));
            if (rid == 0) {
                if (tid == 64)
                    astore(FL + FL_GA + g * 32 + r, (u32)t);
                if (evenT) {   // posted; drained by next tick's WAITVM0
                    u32* gp = (u32*)(h0g + (size_t)(t & 31) * SLOTH);
                    int bi0 = (b * 1024 + w32 + ecc) >> 1;
                    astore(gp + bi0,     hvA);
                    astore(gp + bi0 + 8, hvB);
                }
            } else {
                if (tid == 64)   // L1a progress -> hpart backpressure for L1b
                    astore(FL + FL_GD + g * 32 + r, (u32)t);
            }
        }
        WAITVM0();
        if (tid == 64) {
            u32* fin = FL + ((rid == 0) ? FL_GA : FL_GD) + g * 32 + r;
            astore(fin, 512u);
        }
    } else {
        // =============== PRODUCERS (L0b: xpart, L1b: hpart) ===============
        float* ship  = (rid == 2) ? xpart : hpart;
        u32* myflag  = FL + ((rid == 2) ? FL_GB : FL_GLB) + g * 32 + r;
        u32* gA      = FL + FL_GA + g * 32;
        u32* gD      = FL + FL_GD + g * 32;

        for (int t = 0; t < 512; ++t) {
            if (wid == 0) {
                const u32* pp; unsigned tgt;
                if (rid == 3) {
                    // lanes<32: h0(t) durable; lane 32: hpart backpressure (L1a)
                    pp  = (lane < 32) ? (gA + lane) : (gD + r);
                    tgt = (lane < 32) ? (unsigned)(t + 1)
                        : ((lane == 32 && t >= 7) ? (unsigned)(t - 6) : 0u);
                } else {
                    pp  = gA + r;
                    tgt = (lane == 0 && t >= 7) ? (unsigned)(t - 6) : 0u;
                }
                for (;;) {
                    unsigned v = aload(pp);
                    if (__all((int)(v >= tgt))) break;
                    __builtin_amdgcn_s_sleep(2);
                }
            }
            WAITVM0();   // drain own ship(t-1)
            barlg();
            if (tid == 0 && t > 0)
                astore(myflag, (u32)t);

            f32x4 acc[8];
#pragma unroll
            for (int i = 0; i < 8; ++i) acc[i] = (f32x4){0.f, 0.f, 0.f, 0.f};
            if (rid == 3) {
                const ush* bp = h0g + (size_t)(t & 31) * SLOTH
                              + (size_t)rowL * 1024 + q4 * 8;
#pragma unroll
                for (int j = 0; j < 8; ++j) {
                    int kb = kq + 4 * j;
                    bf16x8 bf = ldh(bp + kb * 32);   // agent IC read (proven)
#pragma unroll
                    for (int gt = 0; gt < 8; ++gt) {
                        bf16x8 a = (j < 4) ? Afrag[(kb * 8 + gt) * 64 + lane] : rf[j - 4][gt];
                        acc[gt] = mfma16(a, bf, acc[gt]);
                    }
                }
            } else {
                const ush* bp = xs + (size_t)(t * 64 + g * 32 + rowL) * 512 + q4 * 8;
#pragma unroll
                for (int j = 0; j < 4; ++j) {
                    int kb = kq + 4 * j;
                    bf16x8 bf = *(const bf16x8*)(bp + kb * 32);
#pragma unroll
                    for (int gt = 0; gt < 8; ++gt)
                        acc[gt] = mfma16(Afrag[(kb * 8 + gt) * 64 + lane], bf, acc[gt]);
                }
            }

#pragma unroll
            for (int h = 0; h < 2; ++h) {
                if (kq < 2) {
#pragma unroll
                    for (int gt2 = 0; gt2 < 4; ++gt2)
#pragma unroll
                        for (int r2 = 0; r2 < 4; ++r2)
                            gws[(size_t)((bt * 2 + kq) * 4 + gt2) * 321
                                + (q4 * 4 + r2) * 20 + n16] = acc[h * 4 + gt2][r2];
                }
                barlg();
                if (kq >= 2) {
#pragma unroll
                    for (int gt2 = 0; gt2 < 4; ++gt2)
#pragma unroll
                        for (int r2 = 0; r2 < 4; ++r2)
                            gws[(size_t)((bt * 2 + (kq - 2)) * 4 + gt2) * 321
                                + (q4 * 4 + r2) * 20 + n16] += acc[h * 4 + gt2][r2];
                }
                barlg();

                int cc  = ecc + 16 * h;
                int gt2 = (cc >> 2) & 3;
                int s2  = cc & 3;
                const float* g0 = gws + (size_t)((btE * 2 + 0) * 4 + gt2) * 321 + s2 * 20 + nE;
                const float* g1 = gws + (size_t)((btE * 2 + 1) * 4 + gt2) * 321 + s2 * 20 + nE;
                float* sp = ship + (size_t)(t & 7) * SLOTP + (size_t)b * 4096 + w32 + cc;
                astoref(sp + 0,    g0[0]   + g1[0]);
                astoref(sp + 1024, g0[80]  + g1[80]);
                astoref(sp + 2048, g0[160] + g1[160]);
                astoref(sp + 3072, g0[240] + g1[240]);
                barlg();   // gws reuse guard
            }
        }
        WAITVM0();
        if (tid == 0)
            astore(myflag, 513u);
    }
}

// ====================== kernel: discover placement, dispatch ================
__global__ __launch_bounds__(512) void lstm_kernel_df(
    const ush* __restrict__ xs, char* __restrict__ ws,
    const float* __restrict__ W0, const float* __restrict__ b0,
    const float* __restrict__ W1, const float* __restrict__ b1)
{
    extern __shared__ char smem[];
    const int wg = blockIdx.x, tid = threadIdx.x;
    __shared__ int s_mode;
    u32* FL = (u32*)(ws + OFF_FL);

    if (tid == 0) {
        u32 xcc;
        asm volatile("s_getreg_b32 %0, hwreg(HW_REG_XCC_ID)" : "=s"(xcc));
        u32 ok = ((int)(xcc & 7) == (wg & 7)) ? 1u : 0u;
        __hip_atomic_fetch_add(FL + FL_DISC, (1u << 9) | ok,
                               __ATOMIC_RELAXED, __HIP_MEMORY_SCOPE_AGENT);
        u32 v = 0; int it = 0;
        for (;;) {
            v = aload(FL + FL_DISC);
            if ((v >> 9) >= 256) break;
            if (++it > (1 << 20)) break;
            __builtin_amdgcn_s_sleep(8);
        }
        s_mode = ((v & 511u) == 256u) ? 1 : 0;
    }
    __syncthreads();
    const int mode = s_mode;

    if (mode) {
        run_local(smem, ws, xs, W0, b0, W1, b1, wg, tid);
    } else {
        fallback_df(smem, xs,
                    (ush*)(ws + 33554432), (ush*)(ws + 50331648),
                    (float*)(ws + OFF_H1F), (u32*)(ws + OFF_BAR),
                    W0, b0, W1, b1, wg, tid);
    }
}

// ---------------- persistent LSTM kernel: round-3 FALLBACK (small ws) ------
__global__ __launch_bounds__(512) void lstm_kernel_fb(
    const ush* __restrict__ xs,
    ush* __restrict__ h0buf,
    ush* __restrict__ h1buf,
    float* __restrict__ h1f,
    u32* __restrict__ bar,
    const float* __restrict__ W0, const float* __restrict__ b0,
    const float* __restrict__ W1, const float* __restrict__ b1)
{
    extern __shared__ char smem[];
    bf16x8* Afrag = (bf16x8*)smem;
    float*  gws   = (float*)(smem + LDS_GWS_OFF);

    const int wg  = blockIdx.x;
    const int tid = threadIdx.x;
    const bool isL1 = (wg >= 128);
    const int w   = isL1 ? wg - 128 : wg;
    const int w8  = w * 8;
    const int nk  = isL1 ? 64 : 48;
    const float* W = isL1 ? W1 : W0;
    const int wstride = isL1 ? 2048 : 1536;
    const float* bias = isL1 ? b1 : b0;

    for (int f = tid; f < nk * 128; f += 512) {
        int kblk = f >> 7;
        int rr   = f & 127;
        int mt   = rr >> 6;
        int lane = rr & 63;
        int m16  = lane & 15;
        int q    = lane >> 4;
        int c    = m16 >> 2;
        int ul   = mt * 4 + (m16 & 3);
        int grow = c * 1024 + w8 + ul;
        const float* src = W + (size_t)grow * wstride + kblk * 32 + q * 8;
        bf16x8 v;
#pragma unroll
        for (int i = 0; i < 8; ++i) v[i] = (short)f2bf(src[i]);
        Afrag[f] = v;
    }

    const int lane = tid & 63;
    const int wid  = tid >> 6;
    const int wv   = wid & 3;
    const int kh   = tid >> 8;
    const int n16  = lane & 15;
    const int q4   = lane >> 4;
    const int brow = wv * 16 + n16;

    float bi[2][4];
#pragma unroll
    for (int cell = 0; cell < 2; ++cell) {
        int j = w8 + q4 * 2 + cell;
#pragma unroll
        for (int c = 0; c < 4; ++c) bi[cell][c] = bias[c * 1024 + j];
    }
    float cst0 = 0.f, cst1 = 0.f;

    __syncthreads();

    f32x4 acc0 = (f32x4){0.f, 0.f, 0.f, 0.f};
    f32x4 acc1 = (f32x4){0.f, 0.f, 0.f, 0.f};

    if (!isL1) {
        const ush* xsp = xs + ((size_t)brow) * 512 + q4 * 8;
        int k0 = kh ? 8 : 0;
#pragma unroll
        for (int kb2 = 0; kb2 < 8; ++kb2) {
            int kb = k0 + kb2;
            bf16x8 bf = *(const bf16x8*)(xsp + kb * 32);
            acc0 = mfma16(Afrag[(kb * 2 + 0) * 64 + lane], bf, acc0);
            acc1 = mfma16(Afrag[(kb * 2 + 1) * 64 + lane], bf, acc1);
        }
    }

    for (int tick = 0; tick < 513; ++tick) {
        if (tick > 0) {
            unsigned target = (unsigned)tick;
            if (wg == 0) {
                if (tid < 256) {
                    while (aload(&bar[tid * 8]) < target)
                        __builtin_amdgcn_s_sleep(1);
                }
                __syncthreads();
                if (tid < 8)
                    astore(&bar[RELIDX + tid * 32], target);
            } else {
                if (tid == 0) {
                    while (aload(&bar[RELIDX + (wg & 7) * 32]) < target)
                        __builtin_amdgcn_s_sleep(1);
                }
                __syncthreads();
            }
            asm volatile("" ::: "memory");
        }

        int t = isL1 ? (tick - 1) : tick;
        if (t >= 0 && t < 512) {
            const int p = t & 1;

            if (!isL1) {
                const ush* hp = h0buf + (size_t)(p ^ 1) * 65536 + (size_t)brow * 1024 + q4 * 8;
                int k0 = kh ? 32 : 16;
#pragma unroll 8
                for (int kb2 = 0; kb2 < 16; ++kb2) {
                    int kb = k0 + kb2;
                    bf16x8 bf = ldh(hp + (kb - 16) * 32);
                    acc0 = mfma16(Afrag[(kb * 2 + 0) * 64 + lane], bf, acc0);
                    acc1 = mfma16(Afrag[(kb * 2 + 1) * 64 + lane], bf, acc1);
                }
            } else if (kh == 0) {
                const ush* hp0 = h0buf + (size_t)p * 65536 + (size_t)brow * 1024 + q4 * 8;
#pragma unroll 8
                for (int kb = 0; kb < 32; ++kb) {
                    bf16x8 bf = ldh(hp0 + kb * 32);
                    acc0 = mfma16(Afrag[(kb * 2 + 0) * 64 + lane], bf, acc0);
                    acc1 = mfma16(Afrag[(kb * 2 + 1) * 64 + lane], bf, acc1);
                }
            } else {
                const ush* hp1 = h1buf + (size_t)(p ^ 1) * 65536 + (size_t)brow * 1024 + q4 * 8;
#pragma unroll 8
                for (int kb = 32; kb < 64; ++kb) {
                    bf16x8 bf = ldh(hp1 + (kb - 32) * 32);
                    acc0 = mfma16(Afrag[(kb * 2 + 0) * 64 + lane], bf, acc0);
                    acc1 = mfma16(Afrag[(kb * 2 + 1) * 64 + lane], bf, acc1);
                }
            }

            float* gq = gws + wid * 512;
#pragma unroll
            for (int rr = 0; rr < 4; ++rr) {
                gq[      q4 * 64 + rr * 16 + n16] = acc0[rr];
                gq[256 + q4 * 64 + rr * 16 + n16] = acc1[rr];
            }
            __syncthreads();

            if (kh == 0) {
                ush* hw = (isL1 ? h1buf : h0buf) + (size_t)p * 65536;
                ush hbits[2];
                float hflt[2];
#pragma unroll
                for (int cell = 0; cell < 2; ++cell) {
                    int ul = q4 * 2 + cell;
                    int mt = ul >> 2;
                    int rr = ul & 3;
                    const float* g0 = gws + wv * 512 + mt * 256;
                    const float* g1 = gws + (wv + 4) * 512 + mt * 256;
                    float xi = g0[0 * 64 + rr * 16 + n16] + g1[0 * 64 + rr * 16 + n16] + bi[cell][0];
                    float xf = g0[1 * 64 + rr * 16 + n16] + g1[1 * 64 + rr * 16 + n16] + bi[cell][1];
                    float xg = g0[2 * 64 + rr * 16 + n16] + g1[2 * 64 + rr * 16 + n16] + bi[cell][2];
                    float xo = g0[3 * 64 + rr * 16 + n16] + g1[3 * 64 + rr * 16 + n16] + bi[cell][3];
                    float si = fsigm(xi);
                    float sf = fsigm(xf);
                    float tg = ftanh(xg);
                    float so = fsigm(xo);
                    float cprev = cell ? cst1 : cst0;
                    float cn = sf * cprev + si * tg;
                    if (cell) cst1 = cn; else cst0 = cn;
                    float h = so * ftanh(cn);
                    hflt[cell]  = h;
                    hbits[cell] = f2bf(h);
                }
                u32 hv = (u32)hbits[0] | ((u32)hbits[1] << 16);
                u32* hp32 = (u32*)(hw + (size_t)brow * 1024 + w8 + q4 * 2);
                astore(hp32, hv);
                if (isL1 && t == 511) {
                    h1f[(size_t)brow * 1024 + w8 + q4 * 2 + 0] = hflt[0];
                    h1f[(size_t)brow * 1024 + w8 + q4 * 2 + 1] = hflt[1];
                }
            }
            __syncthreads();
        }

        if (tick < 512) {
            if (tid == 0) {
                asm volatile("s_waitcnt vmcnt(0)" ::: "memory");
                astore(&bar[wg * 8], (unsigned)(tick + 1));
            }
            acc0 = (f32x4){0.f, 0.f, 0.f, 0.f};
            acc1 = (f32x4){0.f, 0.f, 0.f, 0.f};
            int tn = tick + 1;
            if (!isL1 && tn < 512) {
                const ush* xsp = xs + ((size_t)(tn * 64 + brow)) * 512 + q4 * 8;
                int k0 = kh ? 8 : 0;
#pragma unroll
                for (int kb2 = 0; kb2 < 8; ++kb2) {
                    int kb = k0 + kb2;
                    bf16x8 bf = *(const bf16x8*)(xsp + kb * 32);
                    acc0 = mfma16(Afrag[(kb * 2 + 0) * 64 + lane], bf, acc0);
                    acc1 = mfma16(Afrag[(kb * 2 + 1) * 64 + lane], bf, acc1);
                }
            }
        }
    }
}

// ---------------- classifier: out = h1f @ V.T + bV -------------------------
__global__ __launch_bounds__(64) void cls_kernel(
    const float* __restrict__ h1f, const float* __restrict__ V,
    const float* __restrict__ bV, float* __restrict__ out)
{
    int b = blockIdx.x;
    int lane = threadIdx.x;
    float p[10];
#pragma unroll
    for (int c = 0; c < 10; ++c) p[c] = 0.f;
    for (int k = lane; k < 1024; k += 64) {
        float h = h1f[(size_t)b * 1024 + k];
#pragma unroll
        for (int c = 0; c < 10; ++c) p[c] += h * V[(size_t)c * 1024 + k];
    }
#pragma unroll
    for (int c = 0; c < 10; ++c) {
        float v = p[c];
#pragma unroll
        for (int off = 32; off > 0; off >>= 1) v += __shfl_down(v, off);
        if (lane == 0) out[b * 10 + c] = v + bV[c];
    }
}

// ---------------- launch ---------------------------------------------------
extern "C" void kernel_launch(void* const* d_in, const int* in_sizes, int n_in,
                              void* d_out, int out_size, void* d_ws, size_t ws_size,
                              hipStream_t stream)
{
    const int*   x   = (const int*)d_in[0];
    const float* emb = (const float*)d_in[1];
    const float* W0  = (const float*)d_in[2];
    const float* b0  = (const float*)d_in[3];
    const float* W1  = (const float*)d_in[4];
    const float* b1  = (const float*)d_in[5];
    const float* V   = (const float*)d_in[6];
    const float* bV  = (const float*)d_in[7];
    float* out = (float*)d_out;

    char* ws = (char*)d_ws;
    ush* xs = (ush*)ws;

    if (ws_size >= 67387392ULL) {
        float* h1f = (float*)(ws + OFF_H1F);
        u32*   bar = (u32*)(ws + OFF_BAR);
        u32*   fl  = (u32*)(ws + OFF_FL);

        hipLaunchKernelGGL(init_kernel, dim3(16), dim3(256), 0, stream, bar, 4096);
        hipLaunchKernelGGL(init_kernel, dim3(4),  dim3(256), 0, stream, fl, 1024);
        hipLaunchKernelGGL(embed_kernel, dim3(8192), dim3(256), 0, stream, x, emb, xs);
        hipLaunchKernelGGL(lstm_kernel_df, dim3(256), dim3(512), LDS_LOCAL_TOTAL, stream,
                           xs, ws, W0, b0, W1, b1);
        hipLaunchKernelGGL(cls_kernel, dim3(64), dim3(64), 0, stream, h1f, V, bV, out);
    } else {
        char* dyn = ws + 33554432;
        ush*  h0  = (ush*)(dyn);
        ush*  h1  = (ush*)(dyn + 262144);
        float* h1f = (float*)(dyn + 524288);
        u32*  bar = (u32*)(dyn + 786432);

        hipLaunchKernelGGL(init_kernel, dim3(780), dim3(256), 0, stream,
                           (u32*)dyn, 199680);
        hipLaunchKernelGGL(embed_kernel, dim3(8192), dim3(256), 0, stream, x, emb, xs);
        hipLaunchKernelGGL(lstm_kernel_fb, dim3(256), dim3(512), LDS_FB_TOTAL, stream,
                           xs, h0, h1, h1f, bar, W0, b0, W1, b1);
        hipLaunchKernelGGL(cls_kernel, dim3(64), dim3(64), 0, stream, h1f, V, bV, out);
    }
}

// Round 6
// 2955.484 us; speedup vs baseline: 1.9396x; 1.9396x over previous
//
#include <hip/hip_runtime.h>
#include <stdint.h>

// ---------------------------------------------------------------------------
// 2-layer LSTM, B=64, T=512, E=512, H=1024, then [64,1024]@V.T+bV -> [64,10].
//
// Round 10: revert to proven R7 decomposition (G=2 batch groups x 64 col-WGs
// x 2 layers, C=16 cols/WG, IC-mediated h rings, banked flags) — the R8/R9
// XCD-cluster experiment is falsified: K-split requires f32 gate-partial
// shipping that is 16x heavier than h (WRITE_SIZE 222->1278 MB, dur 5.7ms).
// Change vs R7: conflict-free gws reduce layout derived from bank equations.
//   tile [bt][kp][gt] = [16 batch][4 r2] floats, stride 264 (pad 8):
//   - writer addr = T*264 + lane*4 -> contiguous b128 per wave (0-conflict),
//     reduce = 4x ds_write_b128 / RMW-b128 (was 16/32 scalar, 4-way aliased)
//   - epilogue read banks = egt*8 + en*4 + es -> <=2-way (free, m136)
// R7 measured 1.007e8 SQ_LDS_BANK_CONFLICT; prediction <=2e7.
// ---------------------------------------------------------------------------

typedef __attribute__((ext_vector_type(8))) short bf16x8;
typedef __attribute__((ext_vector_type(4))) float f32x4;
typedef unsigned short ush;
typedef unsigned int u32;

__device__ __forceinline__ ush f2bf(float x) {
    unsigned u = __float_as_uint(x);
    u = (u + 0x7FFFu + ((u >> 16) & 1u)) >> 16;   // RNE
    return (ush)u;
}

__device__ __forceinline__ f32x4 mfma16(bf16x8 a, bf16x8 b, f32x4 c) {
    return __builtin_amdgcn_mfma_f32_16x16x32_bf16(a, b, c, 0, 0, 0);
}

__device__ __forceinline__ float fsigm(float x) {
    x = fminf(fmaxf(x, -60.f), 60.f);
    return __builtin_amdgcn_rcpf(1.f + __expf(-x));
}
__device__ __forceinline__ float ftanh(float x) {
    x = fminf(fmaxf(x, -15.f), 15.f);
    float e = __expf(-2.f * x);
    return (1.f - e) * __builtin_amdgcn_rcpf(1.f + e);
}

// ---- proven access primitives --------------------------------------------
__device__ __forceinline__ u32 aload(const u32* p) {
    return __hip_atomic_load(p, __ATOMIC_RELAXED, __HIP_MEMORY_SCOPE_AGENT);
}
__device__ __forceinline__ void astore(u32* p, u32 v) {
    __hip_atomic_store(p, v, __ATOMIC_RELAXED, __HIP_MEMORY_SCOPE_AGENT);
}
// agent-scope 16B load (IC-direct, fallback path)
__device__ __forceinline__ bf16x8 ldh(const ush* p) {
    union { unsigned long long q[2]; bf16x8 v; } u;
    unsigned long long* a = (unsigned long long*)p;
    u.q[0] = __hip_atomic_load(a + 0, __ATOMIC_RELAXED, __HIP_MEMORY_SCOPE_AGENT);
    u.q[1] = __hip_atomic_load(a + 1, __ATOMIC_RELAXED, __HIP_MEMORY_SCOPE_AGENT);
    return u.v;
}

__device__ __forceinline__ void poll64(const u32* base, int lane, unsigned target) {
    const u32* p = base + lane;
    for (;;) {
        unsigned a = aload(p);
        if (__all((int)(a >= target))) break;
        __builtin_amdgcn_s_sleep(2);
    }
}
__device__ __forceinline__ void poll128(const u32* base, int lane, unsigned target) {
    const u32* p0 = base + lane;
    const u32* p1 = base + 64 + lane;
    for (;;) {
        unsigned a = aload(p0);
        unsigned b = aload(p1);
        if (__all((int)((a >= target) && (b >= target)))) break;
        __builtin_amdgcn_s_sleep(2);
    }
}

// ---------------- embedding gather + bf16 convert --------------------------
__global__ __launch_bounds__(256) void embed_kernel(
    const int* __restrict__ x, const float* __restrict__ emb,
    ush* __restrict__ xs)
{
    int e = blockIdx.x * 256 + threadIdx.x;
    int t  = e >> 12;
    int rr = e & 4095;
    int b  = rr >> 6;
    int k8 = (rr & 63) << 3;
    int tok = x[b * 512 + t];
    const float* src = emb + (size_t)tok * 512 + k8;
    ush* dst = xs + ((size_t)(t * 64 + b)) * 512 + k8;
#pragma unroll
    for (int i = 0; i < 8; ++i) dst[i] = f2bf(src[i]);
}

__global__ __launch_bounds__(256) void init_kernel(u32* __restrict__ p, int n)
{
    int i = blockIdx.x * 256 + threadIdx.x;
    if (i < n) p[i] = 0u;
}

// ---- layout ---------------------------------------------------------------
#define OFF_H1F 67108864ULL
#define OFF_BAR 67371008ULL
// fallback (R3) defines
#define LDS_GWS_OFF 131072
#define RELIDX      2048
#define RING_MASK   127
#define SLOT_USH    65536
#define NBANK       16
// new gws: 16 tiles x 264 floats (pad 8) after 131072B Afrag
#define GT_STRIDE   264
#define LDS_DF_TOTAL (131072 + 16 * GT_STRIDE * 4)   // 147968
#define LDS_FB_TOTAL 148480

// ---------------- persistent LSTM kernel: DATAFLOW (R7 + new gws) ----------
__global__ __launch_bounds__(512) void lstm_kernel_df(
    const ush* __restrict__ xs,
    ush* __restrict__ h0ring,  // [128][64][1024] bf16
    ush* __restrict__ h1ring,  // [128][64][1024] bf16
    float* __restrict__ h1f,   // [64][1024] fp32
    u32* __restrict__ bar,
    const float* __restrict__ W0, const float* __restrict__ b0,
    const float* __restrict__ W1, const float* __restrict__ b1)
{
    extern __shared__ char smem[];
    bf16x8* Afrag = (bf16x8*)smem;                 // [kb<32][4 gt][64 lanes]
    float*  gws   = (float*)(smem + LDS_GWS_OFF);  // 16 tiles * 264 floats

    const int wg  = blockIdx.x;
    const int tid = threadIdx.x;
    const bool isL1 = (wg >= 128);
    const int rr  = wg & 127;
    const int g   = rr >> 6;         // batch group 0/1
    const int w   = rr & 63;         // column block (cols 16w..16w+16)
    const int w16 = w * 16;
    const float* W = isL1 ? W1 : W0;
    const int wstride = isL1 ? 2048 : 1536;
    const float* bias = isL1 ? b1 : b0;
    const u32* bk = bar + (wg & (NBANK - 1)) * 256;

    // ---- LDS A-fragments: kb 0..31, 4 gate-tiles, 64 lanes (131072 B) ----
    for (int f = tid; f < 8192; f += 512) {
        int laneE = f & 63;
        int gt    = (f >> 6) & 3;
        int kb    = f >> 8;
        int m16   = laneE & 15;
        int q     = laneE >> 4;
        int c     = m16 >> 2;
        int s     = m16 & 3;
        int grow  = c * 1024 + w16 + gt * 4 + s;
        const float* src = W + (size_t)grow * wstride + kb * 32 + q * 8;
        bf16x8 v;
#pragma unroll
        for (int i = 0; i < 8; ++i) v[i] = (short)f2bf(src[i]);
        Afrag[f] = v;
    }

    const int lane = tid & 63;
    const int wid  = tid >> 6;         // 0..7
    const int bt   = wid & 1;          // batch sub-tile
    const int ksh  = wid >> 1;         // K-quarter 0..3
    const int n16  = lane & 15;
    const int q4   = lane >> 4;
    const int row  = g * 32 + bt * 16 + n16;
    const int nkreg = isL1 ? 8 : 4;

    // ---- register A-fragments: kb = 32 + ksh + 4*jr ----
    bf16x8 rfb[8][4];
    {
        int m16 = lane & 15;
        int q   = lane >> 4;
        int c   = m16 >> 2;
        int s   = m16 & 3;
#pragma unroll
        for (int jr = 0; jr < 8; ++jr) {
            if (jr < nkreg) {
                int kb = 32 + ksh + 4 * jr;
#pragma unroll
                for (int gt = 0; gt < 4; ++gt) {
                    int grow = c * 1024 + w16 + gt * 4 + s;
                    const float* src = W + (size_t)grow * wstride + kb * 32 + q * 8;
                    bf16x8 v;
#pragma unroll
                    for (int i = 0; i < 8; ++i) v[i] = (short)f2bf(src[i]);
                    rfb[jr][gt] = v;
                }
            }
        }
    }

    // ---- epilogue mapping: 1 cell/thread ----
    const int eb   = tid >> 4;        // local batch 0..31
    const int ecol = tid & 15;        // local column 0..15
    const int ebt  = tid >> 8;        // batch sub-tile
    const int en   = eb & 15;
    const int egt  = ecol >> 2;
    const int es   = ecol & 3;
    const int erow = g * 32 + eb;
    float bi[4];
#pragma unroll
    for (int c = 0; c < 4; ++c) bi[c] = bias[c * 1024 + w16 + ecol];
    float cst = 0.f;
    // value (batch n16, gate q4, col gt*4+r2) at T(bt,kp,gt)*264 + (q4*16+n16)*4 + r2
    // reader: T = ebt*8 + kp*4 + egt; offset (c*16+en)*4 + es; c stride 64
    const float* rb0 = gws + (size_t)(ebt * 8 + egt) * GT_STRIDE + en * 4 + es;       // kp=0
    const float* rb1 = rb0 + 4 * GT_STRIDE;                                           // kp=1
    // writer base: T = bt*8 + (ksh&1)*4 + gt; float off = T*264 + lane*4
    float* wb = gws + (size_t)(bt * 8 + (ksh & 1) * 4) * GT_STRIDE + lane * 4;

    __syncthreads();

    f32x4 acc[4];
#pragma unroll
    for (int i = 0; i < 4; ++i) acc[i] = (f32x4){0.f, 0.f, 0.f, 0.f};

    // pre-loop: L0's xs-part for t=0
    if (!isL1) {
        const ush* xsp = xs + ((size_t)row) * 512 + q4 * 8;
#pragma unroll
        for (int j = 0; j < 4; ++j) {
            int kb = ksh + 4 * j;
            bf16x8 bf = *(const bf16x8*)(xsp + kb * 32);
#pragma unroll
            for (int gt = 0; gt < 4; ++gt)
                acc[gt] = mfma16(Afrag[(kb * 4 + gt) * 64 + lane], bf, acc[gt]);
        }
    }

    for (int tick = 0; tick < 513; ++tick) {
        // ---- dependency wait (banked flags) ----
        if (tick > 0) {
            unsigned target = (unsigned)tick;
            if ((tick & RING_MASK) == 0) {
                if (wid == 0)      poll128(bk,       lane, target);
                else if (wid == 4) poll128(bk + 128, lane, target);
                __syncthreads();
                if (wid == 0)
                    __builtin_amdgcn_fence(__ATOMIC_ACQUIRE, "agent");
                __syncthreads();
            } else {
                if (wid == 0)              poll64(bk + g * 64, lane, target);
                else if (isL1 && wid == 4) poll64(bk + 128 + g * 64, lane, target);
                __syncthreads();
            }
        }

        int t = isL1 ? (tick - 1) : tick;
        if (t >= 0 && t < 512) {
            if (!isL1) {
                // h0(t-1): ring slot (t-1)&127
                if (t > 0) {
                    const ush* hp =
                        h0ring + (size_t)((t - 1) & RING_MASK) * SLOT_USH
                               + (size_t)row * 1024 + q4 * 8;
#pragma unroll
                    for (int j = 4; j < 8; ++j) {          // kb 16..31 (LDS)
                        int kb = ksh + 4 * j;
                        bf16x8 bf = *(const bf16x8*)(hp + (kb - 16) * 32);
#pragma unroll
                        for (int gt = 0; gt < 4; ++gt)
                            acc[gt] = mfma16(Afrag[(kb * 4 + gt) * 64 + lane], bf, acc[gt]);
                    }
#pragma unroll
                    for (int j = 0; j < 4; ++j) {          // kb 32..47 (regs)
                        int kb = 32 + ksh + 4 * j;
                        bf16x8 bf = *(const bf16x8*)(hp + (kb - 16) * 32);
#pragma unroll
                        for (int gt = 0; gt < 4; ++gt)
                            acc[gt] = mfma16(rfb[j][gt], bf, acc[gt]);
                    }
                }
            } else {
                // h0(t): ring slot t&127 (LDS frags, kb 0..31)
                const ush* hp0 =
                    h0ring + (size_t)(t & RING_MASK) * SLOT_USH
                           + (size_t)row * 1024 + q4 * 8;
#pragma unroll
                for (int j = 0; j < 8; ++j) {
                    int kb = ksh + 4 * j;
                    bf16x8 bf = *(const bf16x8*)(hp0 + kb * 32);
#pragma unroll
                    for (int gt = 0; gt < 4; ++gt)
                        acc[gt] = mfma16(Afrag[(kb * 4 + gt) * 64 + lane], bf, acc[gt]);
                }
                // h1(t-1): ring slot (t-1)&127 (reg frags, kb 32..63)
                if (t > 0) {
                    const ush* hp1 =
                        h1ring + (size_t)((t - 1) & RING_MASK) * SLOT_USH
                               + (size_t)row * 1024 + q4 * 8;
#pragma unroll
                    for (int j = 0; j < 8; ++j) {
                        int kb = ksh + 4 * j;
                        bf16x8 bf = *(const bf16x8*)(hp1 + kb * 32);
#pragma unroll
                        for (int gt = 0; gt < 4; ++gt)
                            acc[gt] = mfma16(rfb[j][gt], bf, acc[gt]);
                    }
                }
            }

            // ---- K reduce: contiguous b128 per wave (conflict-free) ----
            if (ksh < 2) {
#pragma unroll
                for (int gt = 0; gt < 4; ++gt)
                    *(f32x4*)(wb + gt * GT_STRIDE) = acc[gt];
            }
            __syncthreads();   // (A1)
            if (ksh >= 2) {
#pragma unroll
                for (int gt = 0; gt < 4; ++gt) {
                    f32x4 v = *(const f32x4*)(wb + gt * GT_STRIDE);
                    v += acc[gt];
                    *(f32x4*)(wb + gt * GT_STRIDE) = v;
                }
            }
            __syncthreads();   // (A2)

            // ---- epilogue: one cell per thread (reads <=2-way banks) ----
            float xi = rb0[0]   + rb1[0]   + bi[0];
            float xf = rb0[64]  + rb1[64]  + bi[1];
            float xg = rb0[128] + rb1[128] + bi[2];
            float xo = rb0[192] + rb1[192] + bi[3];
            float si = fsigm(xi);
            float sf = fsigm(xf);
            float tg = ftanh(xg);
            float so = fsigm(xo);
            float cn = sf * cst + si * tg;
            cst = cn;
            float h  = so * ftanh(cn);
            unsigned hb  = (unsigned)f2bf(h);
            unsigned hup = (unsigned)__shfl_down((int)hb, 1);
            if (!(tid & 1)) {
                unsigned hv = hb | (hup << 16);
                ush* hw = (isL1 ? h1ring : h0ring) + (size_t)(t & RING_MASK) * SLOT_USH;
                u32* hp32 = (u32*)(hw + (size_t)erow * 1024 + w16 + ecol);
                astore(hp32, hv);
            }
            if (isL1 && t == 511)
                h1f[(size_t)erow * 1024 + w16 + ecol] = h;
            __syncthreads();   // (B) drain before flag
        }

        // ---- arrive: publish tick to all 16 banks ----
        if (tick < 512) {
            if (tid < NBANK) {
                astore(bar + tid * 256 + (isL1 ? 128 : 0) + g * 64 + w,
                       (unsigned)(tick + 1));
            }
#pragma unroll
            for (int i = 0; i < 4; ++i) acc[i] = (f32x4){0.f, 0.f, 0.f, 0.f};
            int tn = tick + 1;
            if (!isL1 && tn < 512) {    // xs-part overlaps flag propagation
                const ush* xsp = xs + ((size_t)(tn * 64 + row)) * 512 + q4 * 8;
#pragma unroll
                for (int j = 0; j < 4; ++j) {
                    int kb = ksh + 4 * j;
                    bf16x8 bf = *(const bf16x8*)(xsp + kb * 32);
#pragma unroll
                    for (int gt = 0; gt < 4; ++gt)
                        acc[gt] = mfma16(Afrag[(kb * 4 + gt) * 64 + lane], bf, acc[gt]);
                }
            }
        }
    }
}

// ---------------- persistent LSTM kernel: round-3 FALLBACK (small ws) ------
__global__ __launch_bounds__(512) void lstm_kernel_fb(
    const ush* __restrict__ xs,
    ush* __restrict__ h0buf,
    ush* __restrict__ h1buf,
    float* __restrict__ h1f,
    u32* __restrict__ bar,
    const float* __restrict__ W0, const float* __restrict__ b0,
    const float* __restrict__ W1, const float* __restrict__ b1)
{
    extern __shared__ char smem[];
    bf16x8* Afrag = (bf16x8*)smem;
    float*  gws   = (float*)(smem + LDS_GWS_OFF);

    const int wg  = blockIdx.x;
    const int tid = threadIdx.x;
    const bool isL1 = (wg >= 128);
    const int w   = isL1 ? wg - 128 : wg;
    const int w8  = w * 8;
    const int nk  = isL1 ? 64 : 48;
    const float* W = isL1 ? W1 : W0;
    const int wstride = isL1 ? 2048 : 1536;
    const float* bias = isL1 ? b1 : b0;

    for (int f = tid; f < nk * 128; f += 512) {
        int kblk = f >> 7;
        int rr   = f & 127;
        int mt   = rr >> 6;
        int lane = rr & 63;
        int m16  = lane & 15;
        int q    = lane >> 4;
        int c    = m16 >> 2;
        int ul   = mt * 4 + (m16 & 3);
        int grow = c * 1024 + w8 + ul;
        const float* src = W + (size_t)grow * wstride + kblk * 32 + q * 8;
        bf16x8 v;
#pragma unroll
        for (int i = 0; i < 8; ++i) v[i] = (short)f2bf(src[i]);
        Afrag[f] = v;
    }

    const int lane = tid & 63;
    const int wid  = tid >> 6;
    const int wv   = wid & 3;
    const int kh   = tid >> 8;
    const int n16  = lane & 15;
    const int q4   = lane >> 4;
    const int brow = wv * 16 + n16;

    float bi[2][4];
#pragma unroll
    for (int cell = 0; cell < 2; ++cell) {
        int j = w8 + q4 * 2 + cell;
#pragma unroll
        for (int c = 0; c < 4; ++c) bi[cell][c] = bias[c * 1024 + j];
    }
    float cst0 = 0.f, cst1 = 0.f;

    __syncthreads();

    f32x4 acc0 = (f32x4){0.f, 0.f, 0.f, 0.f};
    f32x4 acc1 = (f32x4){0.f, 0.f, 0.f, 0.f};

    if (!isL1) {
        const ush* xsp = xs + ((size_t)brow) * 512 + q4 * 8;
        int k0 = kh ? 8 : 0;
#pragma unroll
        for (int kb2 = 0; kb2 < 8; ++kb2) {
            int kb = k0 + kb2;
            bf16x8 bf = *(const bf16x8*)(xsp + kb * 32);
            acc0 = mfma16(Afrag[(kb * 2 + 0) * 64 + lane], bf, acc0);
            acc1 = mfma16(Afrag[(kb * 2 + 1) * 64 + lane], bf, acc1);
        }
    }

    for (int tick = 0; tick < 513; ++tick) {
        if (tick > 0) {
            unsigned target = (unsigned)tick;
            if (wg == 0) {
                if (tid < 256) {
                    while (aload(&bar[tid * 8]) < target)
                        __builtin_amdgcn_s_sleep(1);
                }
                __syncthreads();
                if (tid < 8)
                    astore(&bar[RELIDX + tid * 32], target);
            } else {
                if (tid == 0) {
                    while (aload(&bar[RELIDX + (wg & 7) * 32]) < target)
                        __builtin_amdgcn_s_sleep(1);
                }
                __syncthreads();
            }
            asm volatile("" ::: "memory");
        }

        int t = isL1 ? (tick - 1) : tick;
        if (t >= 0 && t < 512) {
            const int p = t & 1;

            if (!isL1) {
                const ush* hp = h0buf + (size_t)(p ^ 1) * 65536 + (size_t)brow * 1024 + q4 * 8;
                int k0 = kh ? 32 : 16;
#pragma unroll 8
                for (int kb2 = 0; kb2 < 16; ++kb2) {
                    int kb = k0 + kb2;
                    bf16x8 bf = ldh(hp + (kb - 16) * 32);
                    acc0 = mfma16(Afrag[(kb * 2 + 0) * 64 + lane], bf, acc0);
                    acc1 = mfma16(Afrag[(kb * 2 + 1) * 64 + lane], bf, acc1);
                }
            } else if (kh == 0) {
                const ush* hp0 = h0buf + (size_t)p * 65536 + (size_t)brow * 1024 + q4 * 8;
#pragma unroll 8
                for (int kb = 0; kb < 32; ++kb) {
                    bf16x8 bf = ldh(hp0 + kb * 32);
                    acc0 = mfma16(Afrag[(kb * 2 + 0) * 64 + lane], bf, acc0);
                    acc1 = mfma16(Afrag[(kb * 2 + 1) * 64 + lane], bf, acc1);
                }
            } else {
                const ush* hp1 = h1buf + (size_t)(p ^ 1) * 65536 + (size_t)brow * 1024 + q4 * 8;
#pragma unroll 8
                for (int kb = 32; kb < 64; ++kb) {
                    bf16x8 bf = ldh(hp1 + (kb - 32) * 32);
                    acc0 = mfma16(Afrag[(kb * 2 + 0) * 64 + lane], bf, acc0);
                    acc1 = mfma16(Afrag[(kb * 2 + 1) * 64 + lane], bf, acc1);
                }
            }

            float* gq = gws + wid * 512;
#pragma unroll
            for (int rr = 0; rr < 4; ++rr) {
                gq[      q4 * 64 + rr * 16 + n16] = acc0[rr];
                gq[256 + q4 * 64 + rr * 16 + n16] = acc1[rr];
            }
            __syncthreads();

            if (kh == 0) {
                ush* hw = (isL1 ? h1buf : h0buf) + (size_t)p * 65536;
                ush hbits[2];
                float hflt[2];
#pragma unroll
                for (int cell = 0; cell < 2; ++cell) {
                    int ul = q4 * 2 + cell;
                    int mt = ul >> 2;
                    int rr = ul & 3;
                    const float* g0 = gws + wv * 512 + mt * 256;
                    const float* g1 = gws + (wv + 4) * 512 + mt * 256;
                    float xi = g0[0 * 64 + rr * 16 + n16] + g1[0 * 64 + rr * 16 + n16] + bi[cell][0];
                    float xf = g0[1 * 64 + rr * 16 + n16] + g1[1 * 64 + rr * 16 + n16] + bi[cell][1];
                    float xg = g0[2 * 64 + rr * 16 + n16] + g1[2 * 64 + rr * 16 + n16] + bi[cell][2];
                    float xo = g0[3 * 64 + rr * 16 + n16] + g1[3 * 64 + rr * 16 + n16] + bi[cell][3];
                    float si = fsigm(xi);
                    float sf = fsigm(xf);
                    float tg = ftanh(xg);
                    float so = fsigm(xo);
                    float cprev = cell ? cst1 : cst0;
                    float cn = sf * cprev + si * tg;
                    if (cell) cst1 = cn; else cst0 = cn;
                    float h = so * ftanh(cn);
                    hflt[cell]  = h;
                    hbits[cell] = f2bf(h);
                }
                u32 hv = (u32)hbits[0] | ((u32)hbits[1] << 16);
                u32* hp32 = (u32*)(hw + (size_t)brow * 1024 + w8 + q4 * 2);
                astore(hp32, hv);
                if (isL1 && t == 511) {
                    h1f[(size_t)brow * 1024 + w8 + q4 * 2 + 0] = hflt[0];
                    h1f[(size_t)brow * 1024 + w8 + q4 * 2 + 1] = hflt[1];
                }
            }
            __syncthreads();
        }

        if (tick < 512) {
            if (tid == 0) {
                asm volatile("s_waitcnt vmcnt(0)" ::: "memory");
                astore(&bar[wg * 8], (unsigned)(tick + 1));
            }
            acc0 = (f32x4){0.f, 0.f, 0.f, 0.f};
            acc1 = (f32x4){0.f, 0.f, 0.f, 0.f};
            int tn = tick + 1;
            if (!isL1 && tn < 512) {
                const ush* xsp = xs + ((size_t)(tn * 64 + brow)) * 512 + q4 * 8;
                int k0 = kh ? 8 : 0;
#pragma unroll
                for (int kb2 = 0; kb2 < 8; ++kb2) {
                    int kb = k0 + kb2;
                    bf16x8 bf = *(const bf16x8*)(xsp + kb * 32);
                    acc0 = mfma16(Afrag[(kb * 2 + 0) * 64 + lane], bf, acc0);
                    acc1 = mfma16(Afrag[(kb * 2 + 1) * 64 + lane], bf, acc1);
                }
            }
        }
    }
}

// ---------------- classifier: out = h1f @ V.T + bV -------------------------
__global__ __launch_bounds__(64) void cls_kernel(
    const float* __restrict__ h1f, const float* __restrict__ V,
    const float* __restrict__ bV, float* __restrict__ out)
{
    int b = blockIdx.x;
    int lane = threadIdx.x;
    float p[10];
#pragma unroll
    for (int c = 0; c < 10; ++c) p[c] = 0.f;
    for (int k = lane; k < 1024; k += 64) {
        float h = h1f[(size_t)b * 1024 + k];
#pragma unroll
        for (int c = 0; c < 10; ++c) p[c] += h * V[(size_t)c * 1024 + k];
    }
#pragma unroll
    for (int c = 0; c < 10; ++c) {
        float v = p[c];
#pragma unroll
        for (int off = 32; off > 0; off >>= 1) v += __shfl_down(v, off);
        if (lane == 0) out[b * 10 + c] = v + bV[c];
    }
}

// ---------------- launch ---------------------------------------------------
// RING ws layout (bytes), total 67,387,392:
//   [0, 33554432)            xs  bf16 [512][64][512]
//   +33554432  h0ring bf16 [128][64][1024]   (16777216)
//   +50331648  h1ring bf16 [128][64][1024]   (16777216)
//   +67108864  h1f    fp32 [64][1024]        (262144)
//   +67371008  flags  [16 banks][256] u32    (16384)
extern "C" void kernel_launch(void* const* d_in, const int* in_sizes, int n_in,
                              void* d_out, int out_size, void* d_ws, size_t ws_size,
                              hipStream_t stream)
{
    const int*   x   = (const int*)d_in[0];
    const float* emb = (const float*)d_in[1];
    const float* W0  = (const float*)d_in[2];
    const float* b0  = (const float*)d_in[3];
    const float* W1  = (const float*)d_in[4];
    const float* b1  = (const float*)d_in[5];
    const float* V   = (const float*)d_in[6];
    const float* bV  = (const float*)d_in[7];
    float* out = (float*)d_out;

    char* ws = (char*)d_ws;
    ush* xs = (ush*)ws;

    if (ws_size >= 67387392ULL) {
        ush*  h0r = (ush*)(ws + 33554432);
        ush*  h1r = (ush*)(ws + 50331648);
        float* h1f = (float*)(ws + OFF_H1F);
        u32*  bar = (u32*)(ws + OFF_BAR);

        hipLaunchKernelGGL(init_kernel, dim3(16), dim3(256), 0, stream, bar, 4096);
        hipLaunchKernelGGL(embed_kernel, dim3(8192), dim3(256), 0, stream, x, emb, xs);
        hipLaunchKernelGGL(lstm_kernel_df, dim3(256), dim3(512), LDS_DF_TOTAL, stream,
                           xs, h0r, h1r, h1f, bar, W0, b0, W1, b1);
        hipLaunchKernelGGL(cls_kernel, dim3(64), dim3(64), 0, stream, h1f, V, bV, out);
    } else {
        char* dyn = ws + 33554432;
        ush*  h0  = (ush*)(dyn);
        ush*  h1  = (ush*)(dyn + 262144);
        float* h1f = (float*)(dyn + 524288);
        u32*  bar = (u32*)(dyn + 786432);

        hipLaunchKernelGGL(init_kernel, dim3(780), dim3(256), 0, stream,
                           (u32*)dyn, 199680);
        hipLaunchKernelGGL(embed_kernel, dim3(8192), dim3(256), 0, stream, x, emb, xs);
        hipLaunchKernelGGL(lstm_kernel_fb, dim3(256), dim3(512), LDS_FB_TOTAL, stream,
                           xs, h0, h1, h1f, bar, W0, b0, W1, b1);
        hipLaunchKernelGGL(cls_kernel, dim3(64), dim3(64), 0, stream, h1f, V, bV, out);
    }
}